// Round 5
// baseline (85.077 us; speedup 1.0000x reference)
//
#include <hip/hip_runtime.h>
#include <hip/hip_bf16.h>

#define NB 4
#define NN 2048
#define NF 256
#define LOG2E 1.4426950408889634f

using bf16x8 = __attribute__((ext_vector_type(8))) short;
using f32x4  = __attribute__((ext_vector_type(4))) float;

__device__ __forceinline__ short f2bf(float f) {
    unsigned u = __float_as_uint(f);
    u += 0x7fffu + ((u >> 16) & 1u);   // RNE, finite inputs only
    return (short)(u >> 16);
}
__device__ __forceinline__ unsigned enc_ord(float f) {
    unsigned u = __float_as_uint(f);
    return (u & 0x80000000u) ? ~u : (u | 0x80000000u);
}
__device__ __forceinline__ float dec_ord(unsigned u) {
    unsigned i = (u & 0x80000000u) ? (u & 0x7fffffffu) : ~u;
    return __uint_as_float(i);
}
__device__ __forceinline__ void gll16(const void* g, void* l) {
    __builtin_amdgcn_global_load_lds(
        (const __attribute__((address_space(1))) unsigned int*)g,
        (__attribute__((address_space(3))) unsigned int*)l, 16, 0, 0);
}

// ---- prep: W->W^T bf16, zero maxfd ----
__global__ __launch_bounds__(256) void prep_kernel(
    const float* __restrict__ W, short* __restrict__ WT, unsigned* __restrict__ maxfd)
{
    const int blk = blockIdx.x, tid = threadIdx.x;
    if (blk < (NF*NF)/256) {
        int t = blk*256 + tid;
        int g = t >> 8, f = t & 255;
        WT[t] = f2bf(W[f*NF + g]);        // WT[g][f] = W[f][g]
    } else if (tid < NB) {
        maxfd[tid] = 0u;
    }
}

// ---- work: [0,1024) adj->bitmask pack (ballot, grid-stride);
//            [1024,1536) h = x@W, fs2/fd2 (x LOG2E), maxfd2 ----
__global__ __launch_bounds__(256,4) void work_kernel(
    const int* __restrict__ adj, unsigned long long* __restrict__ adjP,
    const float* __restrict__ x, const short* __restrict__ WT, const float* __restrict__ a,
    short* __restrict__ hT, float* __restrict__ fs2, float* __restrict__ fd2,
    unsigned* __restrict__ maxfd)
{
    if (blockIdx.x < 1024) {
        const int gid = blockIdx.x*256 + threadIdx.x;
        #pragma unroll 4
        for (int idx = gid; idx < NB*NN*NN; idx += 262144) {
            unsigned long long m = __ballot(adj[idx] > 0);
            if ((threadIdx.x & 63) == 0) adjP[idx >> 6] = m;
        }
        return;
    }
    const int hb = blockIdx.x - 1024;
    __shared__ float fs_l[16], fd_l[16];
    const int w  = threadIdx.x >> 6;
    const int l  = threadIdx.x & 63;
    const int lr = l & 15, lg = l >> 4;
    const int b  = hb >> 7;
    const int ib = (hb & 127) * 16;

    if (threadIdx.x < 16) { fs_l[threadIdx.x] = 0.f; fd_l[threadIdx.x] = 0.f; }
    __syncthreads();

    f32x4 acc[4];
    #pragma unroll
    for (int t = 0; t < 4; t++) acc[t] = (f32x4){0.f,0.f,0.f,0.f};

    const float* xrow = x + (size_t)(b*NN + ib + lr) * NF;
    #pragma unroll
    for (int k0 = 0; k0 < NF; k0 += 32) {
        float4 v0 = *(const float4*)(xrow + k0 + 8*lg);
        float4 v1 = *(const float4*)(xrow + k0 + 8*lg + 4);
        bf16x8 af;
        af[0]=f2bf(v0.x); af[1]=f2bf(v0.y); af[2]=f2bf(v0.z); af[3]=f2bf(v0.w);
        af[4]=f2bf(v1.x); af[5]=f2bf(v1.y); af[6]=f2bf(v1.z); af[7]=f2bf(v1.w);
        #pragma unroll
        for (int nt = 0; nt < 4; nt++) {
            int g = w*64 + nt*16 + lr;
            bf16x8 bf = *(const bf16x8*)(WT + (size_t)g*NF + k0 + 8*lg);
            acc[nt] = __builtin_amdgcn_mfma_f32_16x16x32_bf16(af, bf, acc[nt], 0, 0, 0);
        }
    }

    float fsv[4] = {0,0,0,0}, fdv[4] = {0,0,0,0};
    #pragma unroll
    for (int nt = 0; nt < 4; nt++) {
        int g = w*64 + nt*16 + lr;
        float as = a[g], ad = a[NF + g];
        short4 hv;
        hv.x = f2bf(acc[nt][0]); hv.y = f2bf(acc[nt][1]);
        hv.z = f2bf(acc[nt][2]); hv.w = f2bf(acc[nt][3]);
        *(short4*)(hT + ((size_t)(b*NF + g))*NN + ib + lg*4) = hv;
        #pragma unroll
        for (int r = 0; r < 4; r++) { fsv[r] += acc[nt][r]*as; fdv[r] += acc[nt][r]*ad; }
    }
    #pragma unroll
    for (int mask = 1; mask < 16; mask <<= 1) {
        #pragma unroll
        for (int r = 0; r < 4; r++) {
            fsv[r] += __shfl_xor(fsv[r], mask);
            fdv[r] += __shfl_xor(fdv[r], mask);
        }
    }
    if (lr == 0) {
        #pragma unroll
        for (int r = 0; r < 4; r++) {
            atomicAdd(&fs_l[lg*4 + r], fsv[r]);
            atomicAdd(&fd_l[lg*4 + r], fdv[r]);
        }
    }
    __syncthreads();
    if (threadIdx.x < 16) {
        float fsu = fs_l[threadIdx.x] * LOG2E;
        float fdu = fd_l[threadIdx.x] * LOG2E;
        fs2[b*NN + ib + threadIdx.x] = fsu;
        fd2[b*NN + ib + threadIdx.x] = fdu;
        float wm = fdu;
        #pragma unroll
        for (int m = 1; m < 16; m <<= 1) wm = fmaxf(wm, __shfl_xor(wm, m));
        if (threadIdx.x == 0) atomicMax(maxfd + b, enc_ord(wm));
    }
}

// ---- fused: masked softmax + att@h + elu ----
// grid 256 = 4b x 16 itile(128 rows) x 4 fq(64 f-cols). 1024 thr = 16 waves
// = 4 rowg(32 rows) x 4 kt(32-j slice of BK=128). 16 steps.
// P computed straight into A-frag registers (no P-LDS, no redundant exp in-block).
// B tile (64f x 128j) in LDS, 272-B row stride (conflict-free b128 reads, linear gll),
// 2 slots, staged 1 step ahead, one vmcnt(0)+s_barrier per step.
__global__ __launch_bounds__(1024,4) void gat_fused(
    const short* __restrict__ hT, const unsigned char* __restrict__ adjB,
    const float* __restrict__ fs2, const float* __restrict__ fd2,
    const unsigned* __restrict__ maxfd, float* __restrict__ out)
{
    __shared__ __align__(16) char smem[68096];   // staging 2x17408; epi red 64K; ls @65536
    const int tid = threadIdx.x;
    const int w = tid >> 6, l = tid & 63, lr = l & 15, lg = l >> 4;
    const int kt = w & 3, rowg = w >> 2;
    const int blk = blockIdx.x;
    const int b = blk >> 6, itile = (blk & 63) >> 2, fq = blk & 3;
    const int i0 = itile * 128, f0 = fq * 64;

    const short* hTb = hT + (size_t)b * NF * NN + (size_t)f0 * NN;

    // staging source mapping: LDS chunk q -> (row q/17, chunk q%17); chunk 16 = pad (dup 15)
    const int q1 = tid, r1 = q1 / 17, k1 = q1 % 17;
    const short* sb1 = hTb + (size_t)r1 * NN + (k1 == 16 ? 15 : k1) * 8;
    const int q2 = 1024 + l, r2 = q2 / 17, k2 = q2 % 17;
    const short* sb2 = hTb + (size_t)r2 * NN + (k2 == 16 ? 15 : k2) * 8;

    // per-row softmax constants (rows rowg*32 + {lr, lr+16})
    const float mx2 = dec_ord(maxfd[b]);
    const int gi0 = b*NN + i0 + rowg*32 + lr;
    const float fsa = fs2[gi0], fsb = fs2[gi0 + 16];
    const float M0 = fmaxf(fsa + mx2, 0.f), M1 = fmaxf(fsb + mx2, 0.f);
    const float fsM0 = fsa - M0, nM0 = -M0;
    const float fsM1 = fsb - M1, nM1 = -M1;

    const unsigned char* ar0 = adjB + (size_t)gi0 * (NN/8) + kt*4 + lg;
    const unsigned char* ar1 = ar0 + 16*(NN/8);
    const float* fdp = fd2 + b*NN + kt*32 + lg*8;

    const int boff = (lr*17 + kt*4 + lg)*16;    // ds_read base (row lr, chunk kt*4+lg)

    f32x4 acc[2][4];
    #pragma unroll
    for (int i = 0; i < 2; ++i)
        #pragma unroll
        for (int j = 0; j < 4; ++j) acc[i][j] = (f32x4){0.f,0.f,0.f,0.f};
    float lsum0 = 0.f, lsum1 = 0.f;

    auto STAGE = [&](int t) {
        char* dst = smem + (t & 1) * 17408;
        gll16(sb1 + t*128, dst + (w << 10));
        if (w == 0) gll16(sb2 + t*128, dst + 16384);
    };
    auto LOADP = [&](int t, unsigned& m0, unsigned& m1, f32x4& fa, f32x4& fb) {
        m0 = ar0[t*16]; m1 = ar1[t*16];
        fa = *(const f32x4*)(fdp + t*128);
        fb = *(const f32x4*)(fdp + t*128 + 4);
    };
    auto BODY = [&](int t, unsigned m0, unsigned m1, f32x4 fa, f32x4 fb) {
        const char* sb = smem + (t & 1) * 17408;
        bf16x8 b0 = *(const bf16x8*)(sb + boff);
        bf16x8 b1 = *(const bf16x8*)(sb + boff + 4352);
        bf16x8 b2 = *(const bf16x8*)(sb + boff + 8704);
        bf16x8 b3 = *(const bf16x8*)(sb + boff + 13056);
        float fdv[8] = {fa[0],fa[1],fa[2],fa[3],fb[0],fb[1],fb[2],fb[3]};
        float p0[8], p1[8];
        #pragma unroll
        for (int e = 0; e < 8; ++e) {
            float v0 = __builtin_amdgcn_exp2f(fmaxf(fsM0 + fdv[e], nM0));
            float v1 = __builtin_amdgcn_exp2f(fmaxf(fsM1 + fdv[e], nM1));
            v0 = (m0 & (1u << e)) ? v0 : 0.f;
            v1 = (m1 & (1u << e)) ? v1 : 0.f;
            lsum0 += v0; lsum1 += v1;
            p0[e] = v0;  p1[e] = v1;
        }
        union { bf16x8 v; unsigned u[4]; } a0u, a1u;
        #pragma unroll
        for (int d = 0; d < 4; ++d) {
            asm("v_cvt_pk_bf16_f32 %0, %1, %2" : "=v"(a0u.u[d]) : "v"(p0[2*d]), "v"(p0[2*d+1]));
            asm("v_cvt_pk_bf16_f32 %0, %1, %2" : "=v"(a1u.u[d]) : "v"(p1[2*d]), "v"(p1[2*d+1]));
        }
        acc[0][0] = __builtin_amdgcn_mfma_f32_16x16x32_bf16(a0u.v, b0, acc[0][0], 0, 0, 0);
        acc[1][0] = __builtin_amdgcn_mfma_f32_16x16x32_bf16(a1u.v, b0, acc[1][0], 0, 0, 0);
        acc[0][1] = __builtin_amdgcn_mfma_f32_16x16x32_bf16(a0u.v, b1, acc[0][1], 0, 0, 0);
        acc[1][1] = __builtin_amdgcn_mfma_f32_16x16x32_bf16(a1u.v, b1, acc[1][1], 0, 0, 0);
        acc[0][2] = __builtin_amdgcn_mfma_f32_16x16x32_bf16(a0u.v, b2, acc[0][2], 0, 0, 0);
        acc[1][2] = __builtin_amdgcn_mfma_f32_16x16x32_bf16(a1u.v, b2, acc[1][2], 0, 0, 0);
        acc[0][3] = __builtin_amdgcn_mfma_f32_16x16x32_bf16(a0u.v, b3, acc[0][3], 0, 0, 0);
        acc[1][3] = __builtin_amdgcn_mfma_f32_16x16x32_bf16(a1u.v, b3, acc[1][3], 0, 0, 0);
    };
    #define FENCE_SYNC  do { __builtin_amdgcn_sched_barrier(0); \
        asm volatile("s_waitcnt vmcnt(0)" ::: "memory"); \
        __builtin_amdgcn_s_barrier(); \
        __builtin_amdgcn_sched_barrier(0); } while (0)

    unsigned ma0, ma1, mb0, mb1;
    f32x4 faA, fbA, faB, fbB;
    STAGE(0);
    LOADP(0, ma0, ma1, faA, fbA);
    LOADP(1, mb0, mb1, faB, fbB);
    FENCE_SYNC;

    for (int t = 0; t < 16; t += 2) {
        STAGE(t + 1);
        BODY(t, ma0, ma1, faA, fbA);
        if (t + 2 < 16) LOADP(t + 2, ma0, ma1, faA, fbA);
        FENCE_SYNC;
        if (t + 2 < 16) STAGE(t + 2);
        BODY(t + 1, mb0, mb1, faB, fbB);
        if (t + 3 < 16) LOADP(t + 3, mb0, mb1, faB, fbB);
        FENCE_SYNC;
    }

    // ---- epilogue ----
    lsum0 += __shfl_xor(lsum0, 16); lsum0 += __shfl_xor(lsum0, 32);
    lsum1 += __shfl_xor(lsum1, 16); lsum1 += __shfl_xor(lsum1, 32);
    float* ls = (float*)(smem + 65536);          // [4 rowg][2 mt][16 row][4 kt]
    if (l < 16) {
        ls[((rowg*2 + 0)*16 + lr)*4 + kt] = lsum0;
        ls[((rowg*2 + 1)*16 + lr)*4 + kt] = lsum1;
    }

    float* red  = (float*)smem;                  // 32 KB, aliases staging (loop done)
    float* red2 = (float*)(smem + 32768);
    __syncthreads();
    if (kt >= 2) {
        float* dst = (kt == 2) ? red : red2;
        #pragma unroll
        for (int mt = 0; mt < 2; ++mt)
            #pragma unroll
            for (int nt = 0; nt < 4; ++nt)
                #pragma unroll
                for (int r = 0; r < 4; ++r)
                    dst[rowg*2048 + (mt*16 + lg*4 + r)*64 + nt*16 + lr] = acc[mt][nt][r];
    }
    __syncthreads();
    if (kt < 2) {
        const float* srcp = (kt == 0) ? red : red2;
        #pragma unroll
        for (int mt = 0; mt < 2; ++mt)
            #pragma unroll
            for (int nt = 0; nt < 4; ++nt)
                #pragma unroll
                for (int r = 0; r < 4; ++r)
                    acc[mt][nt][r] += srcp[rowg*2048 + (mt*16 + lg*4 + r)*64 + nt*16 + lr];
    }
    __syncthreads();
    if (kt == 1) {
        #pragma unroll
        for (int mt = 0; mt < 2; ++mt)
            #pragma unroll
            for (int nt = 0; nt < 4; ++nt)
                #pragma unroll
                for (int r = 0; r < 4; ++r)
                    red[rowg*2048 + (mt*16 + lg*4 + r)*64 + nt*16 + lr] = acc[mt][nt][r];
    }
    __syncthreads();
    if (kt == 0) {
        float rv[2][4];
        #pragma unroll
        for (int mt = 0; mt < 2; ++mt)
            #pragma unroll
            for (int r = 0; r < 4; ++r) {
                int base = ((rowg*2 + mt)*16 + lg*4 + r)*4;
                float tot = ls[base] + ls[base+1] + ls[base+2] + ls[base+3];
                rv[mt][r] = tot > 0.f ? 1.f / tot : 0.f;
            }
        #pragma unroll
        for (int mt = 0; mt < 2; ++mt)
            #pragma unroll
            for (int nt = 0; nt < 4; ++nt)
                #pragma unroll
                for (int r = 0; r < 4; ++r) {
                    float v = acc[mt][nt][r]
                            + red[rowg*2048 + (mt*16 + lg*4 + r)*64 + nt*16 + lr];
                    v *= rv[mt][r];
                    v = v > 0.f ? v : expm1f(v);
                    int row = i0 + rowg*32 + mt*16 + lg*4 + r;
                    out[(size_t)(b*NN + row)*NF + f0 + nt*16 + lr] = v;
                }
    }
    #undef FENCE_SYNC
}

extern "C" void kernel_launch(void* const* d_in, const int* in_sizes, int n_in,
                              void* d_out, int out_size, void* d_ws, size_t ws_size,
                              hipStream_t stream) {
    const float* x   = (const float*)d_in[0];
    const int*   adj = (const int*)d_in[1];
    const float* W   = (const float*)d_in[2];
    const float* a   = (const float*)d_in[3];
    float* out = (float*)d_out;
    char* ws = (char*)d_ws;

    short* WT       = (short*)(ws);                   // 128 KB
    short* hT       = (short*)(ws + 0x20000);         // 4 MB
    float* fs2      = (float*)(ws + 0x420000);        // 32 KB
    float* fd2      = (float*)(ws + 0x428000);        // 32 KB
    unsigned* maxfd = (unsigned*)(ws + 0x430000);     // 16 B
    unsigned long long* adjP = (unsigned long long*)(ws + 0x440000); // 2 MB

    prep_kernel<<<(NF*NF)/256 + 1, 256, 0, stream>>>(W, WT, maxfd);
    work_kernel<<<1536, 256, 0, stream>>>(adj, adjP, x, WT, a, hT, fs2, fd2, maxfd);
    gat_fused<<<256, 1024, 0, stream>>>(hT, (const unsigned char*)adjP,
                                        fs2, fd2, maxfd, out);
}

// Round 7
// 67.900 us; speedup vs baseline: 1.2530x; 1.2530x over previous
//
#include <hip/hip_runtime.h>
#include <hip/hip_bf16.h>

#define NB 4
#define NN 2048
#define NF 256
#define LOG2E 1.4426950408889634f

using bf16x8 = __attribute__((ext_vector_type(8))) short;
using f32x4  = __attribute__((ext_vector_type(4))) float;

__device__ __forceinline__ short f2bf(float f) {
    unsigned u = __float_as_uint(f);
    u += 0x7fffu + ((u >> 16) & 1u);   // RNE, finite inputs only
    return (short)(u >> 16);
}
__device__ __forceinline__ unsigned enc_ord(float f) {
    unsigned u = __float_as_uint(f);
    return (u & 0x80000000u) ? ~u : (u | 0x80000000u);
}
__device__ __forceinline__ float dec_ord(unsigned u) {
    unsigned i = (u & 0x80000000u) ? (u & 0x7fffffffu) : ~u;
    return __uint_as_float(i);
}
__device__ __forceinline__ void gll16(const void* g, void* l) {
    __builtin_amdgcn_global_load_lds(
        (const __attribute__((address_space(1))) unsigned int*)g,
        (__attribute__((address_space(3))) unsigned int*)l, 16, 0, 0);
}

// ---- pack: adj -> 1-bit mask (ushort per 16), W->W^T bf16, maxfd init ----
__global__ __launch_bounds__(256) void pack_kernel(
    const int* __restrict__ adj, unsigned short* __restrict__ adjB16,
    const float* __restrict__ W, short* __restrict__ WT, unsigned* __restrict__ maxfd)
{
    const int blk = blockIdx.x, tid = threadIdx.x;
    if (blk < 4096) {                       // 1M threads x 16 ints
        const int g = blk*256 + tid;
        const int4* p = (const int4*)(adj + (size_t)g*16);
        int4 v0 = p[0], v1 = p[1], v2 = p[2], v3 = p[3];
        unsigned m = 0;
        m |= (v0.x>0)<<0;  m |= (v0.y>0)<<1;  m |= (v0.z>0)<<2;  m |= (v0.w>0)<<3;
        m |= (v1.x>0)<<4;  m |= (v1.y>0)<<5;  m |= (v1.z>0)<<6;  m |= (v1.w>0)<<7;
        m |= (v2.x>0)<<8;  m |= (v2.y>0)<<9;  m |= (v2.z>0)<<10; m |= (v2.w>0)<<11;
        m |= (v3.x>0)<<12; m |= (v3.y>0)<<13; m |= (v3.z>0)<<14; m |= (v3.w>0)<<15;
        adjB16[g] = (unsigned short)m;
    } else if (blk < 4096 + (NF*NF)/256) {
        int t = (blk - 4096)*256 + tid;
        WT[t] = f2bf(W[(t & 255)*NF + (t >> 8)]);   // WT[g][f] = W[f][g]
    } else if (tid < NB) {
        maxfd[tid] = 0u;
    }
}

// ---- h = x@W (bf16 MFMA, K-pipelined); hT[b][g][i], fs2/fd2 (x LOG2E), maxfd ----
__global__ __launch_bounds__(256,4) void h_kernel(
    const float* __restrict__ x, const short* __restrict__ WT, const float* __restrict__ a,
    short* __restrict__ hT, float* __restrict__ fs2, float* __restrict__ fd2,
    unsigned* __restrict__ maxfd)
{
    __shared__ float fs_l[16], fd_l[16];
    const int w  = threadIdx.x >> 6;
    const int l  = threadIdx.x & 63;
    const int lr = l & 15, lg = l >> 4;
    const int b  = blockIdx.x >> 7;
    const int ib = (blockIdx.x & 127) * 16;

    if (threadIdx.x < 16) { fs_l[threadIdx.x] = 0.f; fd_l[threadIdx.x] = 0.f; }
    __syncthreads();

    f32x4 acc[4];
    #pragma unroll
    for (int t = 0; t < 4; t++) acc[t] = (f32x4){0.f,0.f,0.f,0.f};

    const float* xrow = x + (size_t)(b*NN + ib + lr) * NF + 8*lg;
    const short* wtp  = WT + (size_t)(w*64 + lr) * NF + 8*lg;

    float4 xa[2][2]; bf16x8 bfr[2][4];
    xa[0][0] = *(const float4*)(xrow);
    xa[0][1] = *(const float4*)(xrow + 4);
    #pragma unroll
    for (int nt = 0; nt < 4; nt++) bfr[0][nt] = *(const bf16x8*)(wtp + nt*16*NF);

    #pragma unroll
    for (int ks = 0; ks < 8; ks++) {
        const int cur = ks & 1;
        if (ks < 7) {
            const int nxt = cur ^ 1;
            xa[nxt][0] = *(const float4*)(xrow + (ks+1)*32);
            xa[nxt][1] = *(const float4*)(xrow + (ks+1)*32 + 4);
            #pragma unroll
            for (int nt = 0; nt < 4; nt++)
                bfr[nxt][nt] = *(const bf16x8*)(wtp + nt*16*NF + (ks+1)*32);
        }
        bf16x8 af;
        af[0]=f2bf(xa[cur][0].x); af[1]=f2bf(xa[cur][0].y);
        af[2]=f2bf(xa[cur][0].z); af[3]=f2bf(xa[cur][0].w);
        af[4]=f2bf(xa[cur][1].x); af[5]=f2bf(xa[cur][1].y);
        af[6]=f2bf(xa[cur][1].z); af[7]=f2bf(xa[cur][1].w);
        #pragma unroll
        for (int nt = 0; nt < 4; nt++)
            acc[nt] = __builtin_amdgcn_mfma_f32_16x16x32_bf16(af, bfr[cur][nt], acc[nt], 0, 0, 0);
    }

    float fsv[4] = {0,0,0,0}, fdv[4] = {0,0,0,0};
    #pragma unroll
    for (int nt = 0; nt < 4; nt++) {
        int g = w*64 + nt*16 + lr;
        float as = a[g], ad = a[NF + g];
        short4 hv;
        hv.x = f2bf(acc[nt][0]); hv.y = f2bf(acc[nt][1]);
        hv.z = f2bf(acc[nt][2]); hv.w = f2bf(acc[nt][3]);
        *(short4*)(hT + ((size_t)(b*NF + g))*NN + ib + lg*4) = hv;
        #pragma unroll
        for (int r = 0; r < 4; r++) { fsv[r] += acc[nt][r]*as; fdv[r] += acc[nt][r]*ad; }
    }
    #pragma unroll
    for (int mask = 1; mask < 16; mask <<= 1) {
        #pragma unroll
        for (int r = 0; r < 4; r++) {
            fsv[r] += __shfl_xor(fsv[r], mask);
            fdv[r] += __shfl_xor(fdv[r], mask);
        }
    }
    if (lr == 0) {
        #pragma unroll
        for (int r = 0; r < 4; r++) {
            atomicAdd(&fs_l[lg*4 + r], fsv[r]);
            atomicAdd(&fd_l[lg*4 + r], fdv[r]);
        }
    }
    __syncthreads();
    if (threadIdx.x < 16) {
        float fsu = fs_l[threadIdx.x] * LOG2E;
        float fdu = fd_l[threadIdx.x] * LOG2E;
        fs2[b*NN + ib + threadIdx.x] = fsu;
        fd2[b*NN + ib + threadIdx.x] = fdu;
        float wm = fdu;
        #pragma unroll
        for (int m = 1; m < 16; m <<= 1) wm = fmaxf(wm, __shfl_xor(wm, m));
        if (threadIdx.x == 0) atomicMax(maxfd + b, enc_ord(wm));
    }
}

// ---- fused: masked softmax + att@h + elu ----
// grid 512 = 4b x 32 itile(64 rows) x 4 fq(64 f-cols); 512 thr = 8 waves
// = 2 rowg(32 rows) x 4 kt(32-j slice of BK=128). 16 steps, 3-slot LDS staging,
// counted vmcnt(6) fences (never drain in-flight next-next-tile loads).
// B tile 64f x 128j, chunk-XOR swizzle (c ^= row&15) on both src and read.
// P computed straight into A-frag registers (exp2, mask, cvt_pk).
__global__ __launch_bounds__(512,4) void gat_fused(
    const short* __restrict__ hT, const unsigned char* __restrict__ adjB,
    const float* __restrict__ fs2, const float* __restrict__ fd2,
    const unsigned* __restrict__ maxfd, float* __restrict__ out)
{
    __shared__ __align__(16) char smem[50176];   // 3x16384 staging + 1KB ls
    float* ls = (float*)(smem + 49152);

    const int tid = threadIdx.x;
    const int w = tid >> 6, l = tid & 63, lr = l & 15, lg = l >> 4;
    const int kt = w & 3, rowg = w >> 2;
    const int blk = blockIdx.x;
    const int b = blk >> 7, rest = blk & 127;
    const int itile = rest >> 2, fq = rest & 3;
    const int i0 = itile * 64, f0 = fq * 64;

    const short* hTb = hT + (size_t)b * NF * NN + (size_t)f0 * NN;

    // staging source (inverse-XOR so linear gll dst + XOR read = identity)
    const int q1 = tid, sr1 = q1 >> 4, sc1 = (q1 & 15) ^ (sr1 & 15);
    const int q2 = 512 + tid, sr2 = q2 >> 4, sc2 = (q2 & 15) ^ (sr2 & 15);
    const short* sb1 = hTb + (size_t)sr1 * NN + sc1*8;
    const short* sb2 = hTb + (size_t)sr2 * NN + sc2*8;

    // per-row softmax constants (rows rowg*32 + {lr, lr+16})
    const float mx2 = dec_ord(maxfd[b]);
    const int gi0 = b*NN + i0 + rowg*32 + lr;
    const float fsa = fs2[gi0], fsb = fs2[gi0 + 16];
    const float M0 = fmaxf(fsa + mx2, 0.f), M1 = fmaxf(fsb + mx2, 0.f);
    const float fsM0 = fsa - M0, nM0 = -M0;
    const float fsM1 = fsb - M1, nM1 = -M1;

    const unsigned char* ar0 = adjB + (size_t)gi0 * (NN/8) + kt*4 + lg;
    const unsigned char* ar1 = ar0 + 16*(NN/8);
    const float* fdp = fd2 + b*NN + kt*32 + lg*8;

    const int boff = lr*256 + (((kt*4 + lg) ^ lr) << 4);   // ds_read base (nt via +4096)

    f32x4 acc[2][4];
    #pragma unroll
    for (int i = 0; i < 2; ++i)
        #pragma unroll
        for (int j = 0; j < 4; ++j) acc[i][j] = (f32x4){0.f,0.f,0.f,0.f};
    float lsum0 = 0.f, lsum1 = 0.f;

    auto STAGE = [&](int t, int slot) {
        char* dst = smem + slot * 16384;
        gll16(sb1 + t*128, dst + tid*16);
        gll16(sb2 + t*128, dst + 8192 + tid*16);
    };
    auto LOADP = [&](int t, unsigned& m0, unsigned& m1, f32x4& fa, f32x4& fb) {
        m0 = ar0[t*16]; m1 = ar1[t*16];
        fa = *(const f32x4*)(fdp + t*128);
        fb = *(const f32x4*)(fdp + t*128 + 4);
    };
    auto BODY = [&](int slot, unsigned m0, unsigned m1, const f32x4& fa, const f32x4& fb) {
        const char* sb = smem + slot * 16384;
        bf16x8 b0 = *(const bf16x8*)(sb + boff);
        bf16x8 b1 = *(const bf16x8*)(sb + boff + 4096);
        bf16x8 b2 = *(const bf16x8*)(sb + boff + 8192);
        bf16x8 b3 = *(const bf16x8*)(sb + boff + 12288);
        float fdv[8] = {fa[0],fa[1],fa[2],fa[3],fb[0],fb[1],fb[2],fb[3]};
        float p0[8], p1[8];
        #pragma unroll
        for (int e = 0; e < 8; ++e) {
            float v0 = __builtin_amdgcn_exp2f(fmaxf(fsM0 + fdv[e], nM0));
            float v1 = __builtin_amdgcn_exp2f(fmaxf(fsM1 + fdv[e], nM1));
            v0 = (m0 & (1u << e)) ? v0 : 0.f;
            v1 = (m1 & (1u << e)) ? v1 : 0.f;
            lsum0 += v0; lsum1 += v1;
            p0[e] = v0;  p1[e] = v1;
        }
        union { bf16x8 v; unsigned u[4]; } a0u, a1u;
        #pragma unroll
        for (int d = 0; d < 4; ++d) {
            asm("v_cvt_pk_bf16_f32 %0, %1, %2" : "=v"(a0u.u[d]) : "v"(p0[2*d]), "v"(p0[2*d+1]));
            asm("v_cvt_pk_bf16_f32 %0, %1, %2" : "=v"(a1u.u[d]) : "v"(p1[2*d]), "v"(p1[2*d+1]));
        }
        acc[0][0] = __builtin_amdgcn_mfma_f32_16x16x32_bf16(a0u.v, b0, acc[0][0], 0, 0, 0);
        acc[1][0] = __builtin_amdgcn_mfma_f32_16x16x32_bf16(a1u.v, b0, acc[1][0], 0, 0, 0);
        acc[0][1] = __builtin_amdgcn_mfma_f32_16x16x32_bf16(a0u.v, b1, acc[0][1], 0, 0, 0);
        acc[1][1] = __builtin_amdgcn_mfma_f32_16x16x32_bf16(a1u.v, b1, acc[1][1], 0, 0, 0);
        acc[0][2] = __builtin_amdgcn_mfma_f32_16x16x32_bf16(a0u.v, b2, acc[0][2], 0, 0, 0);
        acc[1][2] = __builtin_amdgcn_mfma_f32_16x16x32_bf16(a1u.v, b2, acc[1][2], 0, 0, 0);
        acc[0][3] = __builtin_amdgcn_mfma_f32_16x16x32_bf16(a0u.v, b3, acc[0][3], 0, 0, 0);
        acc[1][3] = __builtin_amdgcn_mfma_f32_16x16x32_bf16(a1u.v, b3, acc[1][3], 0, 0, 0);
    };
    #define FENCE6 do { __builtin_amdgcn_sched_barrier(0); \
        asm volatile("s_waitcnt vmcnt(6)" ::: "memory"); \
        __builtin_amdgcn_s_barrier(); \
        __builtin_amdgcn_sched_barrier(0); } while (0)

    unsigned ma0, ma1, mb0, mb1;
    f32x4 faA, fbA, faB, fbB;

    // prologue: stage 0,1; fence ensures slot0 + LOADP(0) done
    STAGE(0, 0); LOADP(0, ma0, ma1, faA, fbA);
    STAGE(1, 1); LOADP(1, mb0, mb1, faB, fbB);
    FENCE6;

    int sl0 = 0, sl1 = 1, sl2 = 2;
    for (int t2 = 0; t2 < 14; t2 += 2) {
        // iter t2: consume slot sl0 / setA, stage (t2+2) -> sl2
        STAGE(t2 + 2, sl2);
        BODY(sl0, ma0, ma1, faA, fbA);
        LOADP(t2 + 2, ma0, ma1, faA, fbA);
        FENCE6;
        // iter t2+1: consume slot sl1 / setB, stage (t2+3) -> sl0
        STAGE(t2 + 3, sl0);
        BODY(sl1, mb0, mb1, faB, fbB);
        LOADP(t2 + 3, mb0, mb1, faB, fbB);
        FENCE6;
        int tmp = sl0; sl0 = sl2; sl2 = sl1; sl1 = tmp;
    }
    // t = 14 (slot sl0, setA): staging done (guaranteed by last FENCE6)
    BODY(sl0, ma0, ma1, faA, fbA);
    __builtin_amdgcn_sched_barrier(0);
    asm volatile("s_waitcnt vmcnt(0)" ::: "memory");
    __builtin_amdgcn_s_barrier();
    __builtin_amdgcn_sched_barrier(0);
    // t = 15 (slot sl1, setB)
    BODY(sl1, mb0, mb1, faB, fbB);

    // ---- epilogue ----
    lsum0 += __shfl_xor(lsum0, 16); lsum0 += __shfl_xor(lsum0, 32);
    lsum1 += __shfl_xor(lsum1, 16); lsum1 += __shfl_xor(lsum1, 32);
    if (l < 16) {
        ls[((rowg*2 + 0)*16 + lr)*4 + kt] = lsum0;
        ls[((rowg*2 + 1)*16 + lr)*4 + kt] = lsum1;
    }
    __syncthreads();

    float* red  = (float*)smem;                  // 16 KB each, alias staging (loop done)
    float* red2 = (float*)(smem + 16384);
    if (kt >= 2) {
        float* dst = (kt == 2) ? red : red2;
        #pragma unroll
        for (int mt = 0; mt < 2; ++mt)
            #pragma unroll
            for (int nt = 0; nt < 4; ++nt)
                #pragma unroll
                for (int r = 0; r < 4; ++r)
                    dst[rowg*2048 + (mt*16 + lg*4 + r)*64 + nt*16 + lr] = acc[mt][nt][r];
    }
    __syncthreads();
    if (kt < 2) {
        const float* srcp = (kt == 0) ? red : red2;
        #pragma unroll
        for (int mt = 0; mt < 2; ++mt)
            #pragma unroll
            for (int nt = 0; nt < 4; ++nt)
                #pragma unroll
                for (int r = 0; r < 4; ++r)
                    acc[mt][nt][r] += srcp[rowg*2048 + (mt*16 + lg*4 + r)*64 + nt*16 + lr];
    }
    __syncthreads();
    if (kt == 1) {
        #pragma unroll
        for (int mt = 0; mt < 2; ++mt)
            #pragma unroll
            for (int nt = 0; nt < 4; ++nt)
                #pragma unroll
                for (int r = 0; r < 4; ++r)
                    red[rowg*2048 + (mt*16 + lg*4 + r)*64 + nt*16 + lr] = acc[mt][nt][r];
    }
    __syncthreads();
    if (kt == 0) {
        float rv[2][4];
        #pragma unroll
        for (int mt = 0; mt < 2; ++mt)
            #pragma unroll
            for (int r = 0; r < 4; ++r) {
                int base = ((rowg*2 + mt)*16 + lg*4 + r)*4;
                float tot = ls[base] + ls[base+1] + ls[base+2] + ls[base+3];
                rv[mt][r] = tot > 0.f ? 1.f / tot : 0.f;
            }
        #pragma unroll
        for (int mt = 0; mt < 2; ++mt)
            #pragma unroll
            for (int nt = 0; nt < 4; ++nt)
                #pragma unroll
                for (int r = 0; r < 4; ++r) {
                    float v = acc[mt][nt][r]
                            + red[rowg*2048 + (mt*16 + lg*4 + r)*64 + nt*16 + lr];
                    v *= rv[mt][r];
                    v = v > 0.f ? v : expm1f(v);
                    int row = i0 + rowg*32 + mt*16 + lg*4 + r;
                    out[(size_t)(b*NN + row)*NF + f0 + nt*16 + lr] = v;
                }
    }
    #undef FENCE6
}

extern "C" void kernel_launch(void* const* d_in, const int* in_sizes, int n_in,
                              void* d_out, int out_size, void* d_ws, size_t ws_size,
                              hipStream_t stream) {
    const float* x   = (const float*)d_in[0];
    const int*   adj = (const int*)d_in[1];
    const float* W   = (const float*)d_in[2];
    const float* a   = (const float*)d_in[3];
    float* out = (float*)d_out;
    char* ws = (char*)d_ws;

    short* WT       = (short*)(ws);                   // 128 KB
    short* hT       = (short*)(ws + 0x20000);         // 4 MB
    float* fs2      = (float*)(ws + 0x420000);        // 32 KB
    float* fd2      = (float*)(ws + 0x428000);        // 32 KB
    unsigned* maxfd = (unsigned*)(ws + 0x430000);     // 16 B
    unsigned short* adjB16 = (unsigned short*)(ws + 0x440000); // 2 MB

    pack_kernel<<<4096 + (NF*NF)/256 + 1, 256, 0, stream>>>(adj, adjB16, W, WT, maxfd);
    h_kernel<<<(NB*NN)/16, 256, 0, stream>>>(x, WT, a, hT, fs2, fd2, maxfd);
    gat_fused<<<NB*128, 512, 0, stream>>>(hT, (const unsigned char*)adjB16,
                                          fs2, fd2, maxfd, out);
}